// Round 1
// baseline (1456.230 us; speedup 1.0000x reference)
//
#include <hip/hip_runtime.h>
#include <math.h>

// ---------------------------------------------------------------------------
// B=2048, N=15, C=1024, H=16, HS=64; M = B*N = 30720 rows.
// All GEMMs: A[M][K] bf16 x Bt[N][K] bf16 (weights pre-transposed) -> C.
// gemm_lds: 128x128 block tile, BK=32, DOUBLE-BUFFERED global_load_lds
// (2-phase: stage t+1 before compute t, single vmcnt(0)+s_barrier per step),
// ds_read_b128 fragments, 16x16x32 MFMA, 4 waves x (64x64).
// Epilogue: acc -> per-wave LDS staging -> coalesced float4/ushort8 stores.
// XCD-chunked bijective swizzle (m204) for gridDim.x<=8 launches.
// MFMA verified layouts:
//   A frag : lane holds A[m=lane&15][k=(lane>>4)*8+j], j=0..7
//   B frag : lane holds B[k=(lane>>4)*8+j][n=lane&15]  (== Bt[n][k] rows)
//   D      : lane reg r holds D[row=(lane>>4)*4+r][col=lane&15]
//
// ws-ADAPTIVE: qkv processed in CH chunks of 30720/CH rows
// (CH in {1,2,4,8,16}; chunk multiple of 1920 = lcm(128,15)).
// peak ws = 205,520,896 + 754,974,720/CH bytes  (CH=16 -> 241 MiB).
// ---------------------------------------------------------------------------

typedef __attribute__((ext_vector_type(8))) short short8;
typedef __attribute__((ext_vector_type(8))) unsigned short ush8;
typedef __attribute__((ext_vector_type(4))) float fx4;

#define MROWS 30720

// global(AS1) -> LDS(AS3) 16-byte async copy; LDS dest = wave-uniform base + lane*16
#define GLL16(g, l)                                                         \
    __builtin_amdgcn_global_load_lds(                                       \
        (const __attribute__((address_space(1))) unsigned int*)(g),         \
        (__attribute__((address_space(3))) unsigned int*)(l), 16, 0, 0)

__device__ inline unsigned short f2bf(float f) {
    unsigned int u = __float_as_uint(f);
    unsigned int r = (u + 0x7fffu + ((u >> 16) & 1u)) >> 16;
    return (unsigned short)r;
}
__device__ inline float bf2f(unsigned short s) {
    return __uint_as_float(((unsigned int)s) << 16);
}

// ---------------- weight transpose + bf16 cast:  W[K][N] -> Wt[N][K] --------
__global__ __launch_bounds__(256) void transpose_w(const float* __restrict__ W,
                                                   unsigned short* __restrict__ Wt,
                                                   int K, int N) {
    __shared__ float tile[32][33];
    int bn = blockIdx.x * 32;
    int bk = blockIdx.y * 32;
    int tx = threadIdx.x & 31, ty = threadIdx.x >> 5;   // 32 x 8
    #pragma unroll
    for (int i = ty; i < 32; i += 8)
        tile[i][tx] = W[(size_t)(bk + i) * N + bn + tx];
    __syncthreads();
    #pragma unroll
    for (int i = ty; i < 32; i += 8)
        Wt[(size_t)(bn + i) * K + bk + tx] = f2bf(tile[tx][i]);
}

// ---------------- LayerNorm over C=1024, fp32 in -> bf16 out ---------------
__global__ __launch_bounds__(256) void ln_dual(const float* __restrict__ xa,
                                               const float* __restrict__ ga,
                                               const float* __restrict__ bba,
                                               unsigned short* __restrict__ oa,
                                               const float* __restrict__ xb,
                                               const float* __restrict__ gb,
                                               const float* __restrict__ bbb,
                                               unsigned short* __restrict__ ob) {
    const float* x = blockIdx.y ? xb : xa;
    const float* g = blockIdx.y ? gb : ga;
    const float* bv = blockIdx.y ? bbb : bba;
    unsigned short* out = blockIdx.y ? ob : oa;

    int row = blockIdx.x;
    int t = threadIdx.x;
    const float4* xp = (const float4*)(x + (size_t)row * 1024);
    float4 v = xp[t];
    float s  = v.x + v.y + v.z + v.w;
    float ss = v.x * v.x + v.y * v.y + v.z * v.z + v.w * v.w;
    #pragma unroll
    for (int o = 32; o > 0; o >>= 1) { s += __shfl_down(s, o); ss += __shfl_down(ss, o); }
    __shared__ float ps[4], pss[4], stat[2];
    int wv = t >> 6, ln = t & 63;
    if (ln == 0) { ps[wv] = s; pss[wv] = ss; }
    __syncthreads();
    if (t == 0) {
        float S = ps[0] + ps[1] + ps[2] + ps[3];
        float SS = pss[0] + pss[1] + pss[2] + pss[3];
        float m = S * (1.0f / 1024.0f);
        float var = SS * (1.0f / 1024.0f) - m * m;
        stat[0] = m; stat[1] = rsqrtf(var + 1e-5f);
    }
    __syncthreads();
    float m = stat[0], r = stat[1];
    float4 gg = ((const float4*)g)[t];
    float4 bb = ((const float4*)bv)[t];
    ushort4 o;
    o.x = f2bf((v.x - m) * r * gg.x + bb.x);
    o.y = f2bf((v.y - m) * r * gg.y + bb.y);
    o.z = f2bf((v.z - m) * r * gg.z + bb.z);
    o.w = f2bf((v.w - m) * r * gg.w + bb.w);
    ((ushort4*)(out + (size_t)row * 1024))[t] = o;
}

// ---------------- 2-phase dbuf bf16 MFMA GEMM, fused epilogues -------------
// EPI 0: outB = bf16(acc); gridDim.z==2 selects (A,Bt,outB) vs (A2,Bt2,outB2)
// EPI 1: outF = acc + bias[col] + resid[row][col]        (fp32 out)
// EPI 2: outB = bf16(gelu_exact(acc + bias[col]))
template <int EPI, int K>
__global__ __launch_bounds__(256) void gemm_lds(const unsigned short* __restrict__ A,
                                                const unsigned short* __restrict__ Bt,
                                                const unsigned short* __restrict__ A2,
                                                const unsigned short* __restrict__ Bt2,
                                                const float* __restrict__ bias,
                                                const float* __restrict__ resid,
                                                float* __restrict__ outF,
                                                unsigned short* __restrict__ outB,
                                                unsigned short* __restrict__ outB2,
                                                int N) {
    if (EPI == 0 && blockIdx.z) { A = A2; Bt = Bt2; outB = outB2; }

    // 32 KiB: two 8 KiB A-buffers + two 8 KiB B-buffers. Epilogue staging
    // (20 KiB of fp32) aliases this after the K-loop's final barrier.
    __shared__ __align__(16) char smem[32768];
    unsigned short* lA = (unsigned short*)smem;            // [2][4096]
    unsigned short* lB = (unsigned short*)(smem + 16384);  // [2][4096]

    const int tid = threadIdx.x;
    const int wave = tid >> 6, lane = tid & 63;
    const int rowf = lane & 15, quad = lane >> 4;

    // ---- XCD-chunked bijective swizzle (m204) for narrow grids ----
    // gridDim.x<=8: linear dispatch puts the gridDim.x blocks sharing one
    // A row-panel on different XCDs -> A re-fetched per XCD. Remap so each
    // XCD owns a contiguous run of blocks (x-fastest inside the run).
    // qkv (gridDim.x=24 == 0 mod 8) already pins B col-panels per XCD;
    // leave it identity.
    int bx = blockIdx.x, by = blockIdx.y;
    if (gridDim.x <= 8) {
        int nwg = gridDim.x * gridDim.y;
        int lid = by * gridDim.x + bx;
        int q = nwg >> 3, r = nwg & 7;
        int xcd = lid & 7, pos = lid >> 3;
        int nl = (xcd < r ? xcd * (q + 1) : r * (q + 1) + (xcd - r) * q) + pos;
        bx = nl % gridDim.x;
        by = nl / gridDim.x;
    }

    const int m0 = by * 128;
    const int n0 = bx * 128;
    const int wm0 = (wave >> 1) * 64;         // wave sub-tile inside block
    const int wn0 = (wave & 1) * 64;

    // staging: chunk c = tid + iter*256; row = c>>2, kchunk = (c&3)*8 elements
    const int srow = tid >> 2;                // 0..63
    const int skc  = (tid & 3) * 8;           // 0/8/16/24
    const unsigned short* gA0 = A  + (size_t)(m0 + srow) * K + skc;
    const unsigned short* gA1 = A  + (size_t)(m0 + srow + 64) * K + skc;
    const unsigned short* gB0 = Bt + (size_t)(n0 + srow) * K + skc;
    const unsigned short* gB1 = Bt + (size_t)(n0 + srow + 64) * K + skc;

    fx4 acc[4][4] = {};

    const int NT = K / 32;

    // prologue: tile 0 -> buffer 0 (syncthreads drains vmcnt)
    GLL16(gA0, lA + (size_t)tid * 8);
    GLL16(gA1, lA + (size_t)(tid + 256) * 8);
    GLL16(gB0, lB + (size_t)tid * 8);
    GLL16(gB1, lB + (size_t)(tid + 256) * 8);
    gA0 += 32; gA1 += 32; gB0 += 32; gB1 += 32;
    __syncthreads();

    #pragma unroll 2
    for (int t = 0; t < NT; ++t) {
        const int cur = t & 1, nxt = cur ^ 1;
        // stage tile t+1 while computing tile t (loads in flight over MFMA)
        if (t + 1 < NT) {
            GLL16(gA0, lA + nxt * 4096 + (size_t)tid * 8);
            GLL16(gA1, lA + nxt * 4096 + (size_t)(tid + 256) * 8);
            GLL16(gB0, lB + nxt * 4096 + (size_t)tid * 8);
            GLL16(gB1, lB + nxt * 4096 + (size_t)(tid + 256) * 8);
            gA0 += 32; gA1 += 32; gB0 += 32; gB1 += 32;
        }
        const unsigned short* sA = lA + cur * 4096;
        const unsigned short* sB = lB + cur * 4096;
        short8 a[4], b[4];
        #pragma unroll
        for (int i = 0; i < 4; i++)
            a[i] = *(const short8*)(sA + (wm0 + 16 * i + rowf) * 32 + quad * 8);
        #pragma unroll
        for (int j = 0; j < 4; j++)
            b[j] = *(const short8*)(sB + (wn0 + 16 * j + rowf) * 32 + quad * 8);
        #pragma unroll
        for (int i = 0; i < 4; i++)
            #pragma unroll
            for (int j = 0; j < 4; j++)
                acc[i][j] = __builtin_amdgcn_mfma_f32_16x16x32_bf16(a[i], b[j], acc[i][j], 0, 0, 0);
        // single drain+barrier per K-step: next-tile loads complete here,
        // all waves' ds_reads of buf[cur] complete before it is re-staged.
        asm volatile("s_waitcnt vmcnt(0) lgkmcnt(0)\n\ts_barrier" ::: "memory");
    }

    // ---- epilogue: per-wave LDS transpose -> coalesced vector I/O ----
    // wave-private 16x80 fp32 staging region (aliases dead lA/lB).
    float* st = (float*)smem + wave * 1280;
    const int rl  = lane >> 2;               // 0..15  (local row)
    const int c0l = (lane & 3) * 16;         // 0/16/32/48 (local col base)
    const int colb = n0 + wn0 + c0l;

    #pragma unroll
    for (int i = 0; i < 4; i++) {
        #pragma unroll
        for (int j = 0; j < 4; j++)
            #pragma unroll
            for (int r = 0; r < 4; r++)
                st[(quad * 4 + r) * 80 + 16 * j + rowf] = acc[i][j][r];
        // wave-local RAW on LDS: compiler inserts lgkmcnt; no cross-wave use.
        const int row = m0 + wm0 + 16 * i + rl;
        if (EPI == 1) {
            #pragma unroll
            for (int kk = 0; kk < 4; kk++) {
                float4 v  = *(const float4*)(st + rl * 80 + c0l + 4 * kk);
                float4 bb = *((const float4*)(bias + colb) + kk);
                float4 rr = *((const float4*)(resid + (size_t)row * N + colb) + kk);
                v.x += bb.x + rr.x; v.y += bb.y + rr.y;
                v.z += bb.z + rr.z; v.w += bb.w + rr.w;
                *((float4*)(outF + (size_t)row * N + colb) + kk) = v;
            }
        } else {
            #pragma unroll
            for (int h = 0; h < 2; h++) {
                float4 va = *(const float4*)(st + rl * 80 + c0l + 8 * h);
                float4 vb = *(const float4*)(st + rl * 80 + c0l + 8 * h + 4);
                float f[8] = {va.x, va.y, va.z, va.w, vb.x, vb.y, vb.z, vb.w};
                if (EPI == 2) {
                    float4 ba = *((const float4*)(bias + colb) + 2 * h);
                    float4 bc = *((const float4*)(bias + colb) + 2 * h + 1);
                    float bf[8] = {ba.x, ba.y, ba.z, ba.w, bc.x, bc.y, bc.z, bc.w};
                    #pragma unroll
                    for (int e = 0; e < 8; e++) {
                        float v = f[e] + bf[e];
                        f[e] = 0.5f * v * (1.0f + erff(v * 0.70710678118654752f));
                    }
                }
                ush8 o;
                #pragma unroll
                for (int e = 0; e < 8; e++) o[e] = f2bf(f[e]);
                *(ush8*)(outB + (size_t)row * N + colb + 8 * h) = o;
            }
        }
    }
}

// ---------------- attention: one block per (chunk-local b, h) --------------
__global__ __launch_bounds__(256) void attn_kernel(const unsigned short* __restrict__ Jqkv,
                                                   const unsigned short* __restrict__ Iqkv,
                                                   const float* __restrict__ Wc,
                                                   unsigned short* __restrict__ xout) {
    int b = blockIdx.x >> 4;
    int h = blockIdx.x & 15;
    __shared__ float J[3][15][65];
    __shared__ float I[3][15][65];
    __shared__ float W[64][17];
    __shared__ float P[15][16];

    const unsigned short* Jb = Jqkv + (size_t)b * 15 * 3072 + h * 64;
    const unsigned short* Ib = Iqkv + (size_t)b * 15 * 3072 + h * 64;

    // vectorized 16B loads: 360 chunks of 8 bf16 per stream
    for (int idx = threadIdx.x; idx < 360; idx += 256) {
        int n = idx / 24, rem = idx % 24;
        int r = rem >> 3, d0 = (rem & 7) * 8;
        short8 vj = *(const short8*)(Jb + (size_t)n * 3072 + r * 1024 + d0);
        short8 vi = *(const short8*)(Ib + (size_t)n * 3072 + r * 1024 + d0);
        #pragma unroll
        for (int e = 0; e < 8; e++) {
            J[r][n][d0 + e] = bf2f((unsigned short)vj[e]);
            I[r][n][d0 + e] = bf2f((unsigned short)vi[e]);
        }
    }
    for (int idx = threadIdx.x; idx < 64 * 15; idx += 256)
        W[idx / 15][idx % 15] = Wc[idx];
    __syncthreads();

    for (int idx = threadIdx.x; idx < 225; idx += 256) {
        int q = idx / 15, kk = idx % 15;
        float s = 0.0f;
        #pragma unroll 8
        for (int d = 0; d < 64; d++)
            s += J[0][q][d] * J[1][kk][d] + I[0][q][d] * I[1][kk][d] + I[2][q][d] * W[d][kk];
        P[q][kk] = s * 0.125f;
    }
    __syncthreads();

    if (threadIdx.x < 15) {
        int q = threadIdx.x;
        float mx = -1e30f;
        #pragma unroll
        for (int kk = 0; kk < 15; kk++) mx = fmaxf(mx, P[q][kk]);
        float e[15], sum = 0.0f;
        #pragma unroll
        for (int kk = 0; kk < 15; kk++) { e[kk] = __expf(P[q][kk] - mx); sum += e[kk]; }
        float inv = 1.0f / sum;
        #pragma unroll
        for (int kk = 0; kk < 15; kk++) P[q][kk] = e[kk] * inv;
    }
    __syncthreads();

    // vectorized ushort4 output: 240 chunks of 4
    for (int idx = threadIdx.x; idx < 240; idx += 256) {
        int q = idx >> 4, d0 = (idx & 15) * 4;
        float o0 = 0.0f, o1 = 0.0f, o2 = 0.0f, o3 = 0.0f;
        #pragma unroll
        for (int kk = 0; kk < 15; kk++) {
            float p = P[q][kk];
            o0 += p * J[2][kk][d0 + 0];
            o1 += p * J[2][kk][d0 + 1];
            o2 += p * J[2][kk][d0 + 2];
            o3 += p * J[2][kk][d0 + 3];
        }
        ushort4 o;
        o.x = f2bf(o0); o.y = f2bf(o1); o.z = f2bf(o2); o.w = f2bf(o3);
        *(ushort4*)(xout + ((size_t)b * 15 + q) * 1024 + h * 64 + d0) = o;
    }
}

// ---------------------------------------------------------------------------
extern "C" void kernel_launch(void* const* d_in, const int* in_sizes, int n_in,
                              void* d_out, int out_size, void* d_ws, size_t ws_size,
                              hipStream_t stream) {
    const float* joint_feature    = (const float*)d_in[0];
    const float* relation_feature = (const float*)d_in[1];
    const float* W_Jqkv  = (const float*)d_in[2];
    const float* W_Iqk   = (const float*)d_in[3];
    const float* W_Iconv = (const float*)d_in[4];
    const float* W_proj  = (const float*)d_in[5];
    const float* b_proj  = (const float*)d_in[6];
    const float* g1  = (const float*)d_in[7];
    const float* be1 = (const float*)d_in[8];
    const float* g2  = (const float*)d_in[9];
    const float* be2 = (const float*)d_in[10];
    const float* gj  = (const float*)d_in[11];
    const float* bj  = (const float*)d_in[12];
    const float* W_fc1 = (const float*)d_in[13];
    const float* b_fc1 = (const float*)d_in[14];
    const float* W_fc2 = (const float*)d_in[15];
    const float* b_fc2 = (const float*)d_in[16];

    char* ws = (char*)d_ws;
    // -------- fixed region [0, 205,520,896) --------
    unsigned short* WtJ  = (unsigned short*)(ws + 0);          //  [3072][1024]
    unsigned short* WtI  = (unsigned short*)(ws + 6291456);    //  [3072][1024]
    unsigned short* WtP  = (unsigned short*)(ws + 12582912);   //  [1024][1024]
    unsigned short* WtF1 = (unsigned short*)(ws + 14680064);   //  [512][1024]
    unsigned short* WtF2 = (unsigned short*)(ws + 15728640);   //  [1024][512]
    unsigned short* xj   = (unsigned short*)(ws + 16777216);   //  [M][1024] bf16
    unsigned short* xi   = (unsigned short*)(ws + 79691776);   //  [M][1024] bf16
    unsigned short* xattn = (unsigned short*)(ws + 142606336); //  [M][1024] bf16
    // -------- reused regions --------
    float*          joint = (float*)(ws + 16777216);           // fp32 [M][1024] over dead xj+xi
    unsigned short* yln   = xattn;                             // xattn dead after proj
    unsigned short* h1    = (unsigned short*)(ws + 205520896); // bf16 [M][512]
    // -------- chunked qkv region --------
    int CH = 16;
    {
        const int opts[5] = {1, 2, 4, 8, 16};
        for (int i = 0; i < 5; i++) {
            size_t need = 205520896ull + 754974720ull / (size_t)opts[i];
            if (need <= ws_size) { CH = opts[i]; break; }
        }
    }
    const int Mc = MROWS / CH;                      // multiple of 1920
    const size_t chunkBytes = 754974720ull / (size_t)CH / 2ull;
    unsigned short* Jqkv_c = (unsigned short*)(ws + 205520896);
    unsigned short* Iqkv_c = (unsigned short*)(ws + 205520896 + chunkBytes);

    dim3 blk(256);

    // 1) transpose + bf16-cast weights
    transpose_w<<<dim3(96, 32), blk, 0, stream>>>(W_Jqkv, WtJ, 1024, 3072);
    transpose_w<<<dim3(96, 32), blk, 0, stream>>>(W_Iqk,  WtI, 1024, 3072);
    transpose_w<<<dim3(32, 32), blk, 0, stream>>>(W_proj, WtP, 1024, 1024);
    transpose_w<<<dim3(16, 32), blk, 0, stream>>>(W_fc1, WtF1, 1024, 512);
    transpose_w<<<dim3(32, 16), blk, 0, stream>>>(W_fc2, WtF2, 512, 1024);

    // 2) LN both input streams -> bf16
    ln_dual<<<dim3(MROWS, 2), blk, 0, stream>>>(joint_feature, g1, be1, xj,
                                                relation_feature, g2, be2, xi);

    // 3+4) chunked: qkv GEMM (both streams via grid.z) then attention
    for (int c = 0; c < CH; c++) {
        size_t ro = (size_t)c * Mc * 1024;
        gemm_lds<0, 1024><<<dim3(24, Mc / 128, 2), blk, 0, stream>>>(
            xj + ro, WtJ, xi + ro, WtI, nullptr, nullptr, nullptr, Jqkv_c, Iqkv_c, 3072);
        attn_kernel<<<(Mc / 15) * 16, blk, 0, stream>>>(Jqkv_c, Iqkv_c, W_Iconv, xattn + ro);
    }

    // 5) proj + bias + residual(joint_feature) -> joint (fp32)
    gemm_lds<1, 1024><<<dim3(8, 240), blk, 0, stream>>>(
        xattn, WtP, nullptr, nullptr, b_proj, joint_feature, joint, nullptr, nullptr, 1024);

    // 6) LN(joint) -> yln
    ln_dual<<<dim3(MROWS, 1), blk, 0, stream>>>(joint, gj, bj, yln,
                                                nullptr, nullptr, nullptr, nullptr);

    // 7) fc1 + bias + gelu -> h1 (bf16)
    gemm_lds<2, 1024><<<dim3(4, 240), blk, 0, stream>>>(
        yln, WtF1, nullptr, nullptr, b_fc1, nullptr, nullptr, h1, nullptr, 512);

    // 8) fc2 + bias + residual(joint) -> d_out (fp32)
    gemm_lds<1, 512><<<dim3(8, 240), blk, 0, stream>>>(
        h1, WtF2, nullptr, nullptr, b_fc2, joint, (float*)d_out, nullptr, nullptr, 1024);
}

// Round 2
// 1442.288 us; speedup vs baseline: 1.0097x; 1.0097x over previous
//
#include <hip/hip_runtime.h>
#include <math.h>

// ---------------------------------------------------------------------------
// B=2048, N=15, C=1024, H=16, HS=64; M = B*N = 30720 rows.
// All GEMMs: A[M][K] bf16 x Bt[N][K] bf16 (weights pre-transposed) -> C.
// gemm_lds: 128x128 block tile, BK=32, 3-buffer LDS ring, prefetch depth 2,
// COUNTED vmcnt (8/4/0) so 2 tiles stay in flight across barriers (T4),
// ds_read_b128 fragments, 16x16x32 MFMA, 4 waves x (64x64), setprio on MFMA.
// Epilogue: acc -> per-wave LDS staging (stride 84: 2-way, free) -> coalesced
// float4/ushort8 stores. XCD-chunked bijective swizzle (m204) for gridDim.x<=8.
// MFMA verified layouts:
//   A frag : lane holds A[m=lane&15][k=(lane>>4)*8+j], j=0..7
//   B frag : lane holds B[k=(lane>>4)*8+j][n=lane&15]  (== Bt[n][k] rows)
//   D      : lane reg r holds D[row=(lane>>4)*4+r][col=lane&15]
//
// ws-ADAPTIVE: qkv processed in CH chunks of 30720/CH rows
// (CH in {1,2,4,8,16}; chunk multiple of 1920 = lcm(128,15)).
// peak ws = 205,520,896 + 754,974,720/CH bytes  (CH=16 -> 241 MiB).
// ---------------------------------------------------------------------------

typedef __attribute__((ext_vector_type(8))) short short8;
typedef __attribute__((ext_vector_type(8))) unsigned short ush8;
typedef __attribute__((ext_vector_type(4))) float fx4;

#define MROWS 30720

// global(AS1) -> LDS(AS3) 16-byte async copy; LDS dest = wave-uniform base + lane*16
#define GLL16(g, l)                                                         \
    __builtin_amdgcn_global_load_lds(                                       \
        (const __attribute__((address_space(1))) unsigned int*)(g),         \
        (__attribute__((address_space(3))) unsigned int*)(l), 16, 0, 0)

__device__ inline unsigned short f2bf(float f) {
    unsigned int u = __float_as_uint(f);
    unsigned int r = (u + 0x7fffu + ((u >> 16) & 1u)) >> 16;
    return (unsigned short)r;
}
__device__ inline float bf2f(unsigned short s) {
    return __uint_as_float(((unsigned int)s) << 16);
}

// ---------------- weight transpose + bf16 cast:  W[K][N] -> Wt[N][K] --------
__global__ __launch_bounds__(256) void transpose_w(const float* __restrict__ W,
                                                   unsigned short* __restrict__ Wt,
                                                   int K, int N) {
    __shared__ float tile[32][33];
    int bn = blockIdx.x * 32;
    int bk = blockIdx.y * 32;
    int tx = threadIdx.x & 31, ty = threadIdx.x >> 5;   // 32 x 8
    #pragma unroll
    for (int i = ty; i < 32; i += 8)
        tile[i][tx] = W[(size_t)(bk + i) * N + bn + tx];
    __syncthreads();
    #pragma unroll
    for (int i = ty; i < 32; i += 8)
        Wt[(size_t)(bn + i) * K + bk + tx] = f2bf(tile[tx][i]);
}

// ---------------- LayerNorm over C=1024, fp32 in -> bf16 out ---------------
__global__ __launch_bounds__(256) void ln_dual(const float* __restrict__ xa,
                                               const float* __restrict__ ga,
                                               const float* __restrict__ bba,
                                               unsigned short* __restrict__ oa,
                                               const float* __restrict__ xb,
                                               const float* __restrict__ gb,
                                               const float* __restrict__ bbb,
                                               unsigned short* __restrict__ ob) {
    const float* x = blockIdx.y ? xb : xa;
    const float* g = blockIdx.y ? gb : ga;
    const float* bv = blockIdx.y ? bbb : bba;
    unsigned short* out = blockIdx.y ? ob : oa;

    int row = blockIdx.x;
    int t = threadIdx.x;
    const float4* xp = (const float4*)(x + (size_t)row * 1024);
    float4 v = xp[t];
    float s  = v.x + v.y + v.z + v.w;
    float ss = v.x * v.x + v.y * v.y + v.z * v.z + v.w * v.w;
    #pragma unroll
    for (int o = 32; o > 0; o >>= 1) { s += __shfl_down(s, o); ss += __shfl_down(ss, o); }
    __shared__ float ps[4], pss[4], stat[2];
    int wv = t >> 6, ln = t & 63;
    if (ln == 0) { ps[wv] = s; pss[wv] = ss; }
    __syncthreads();
    if (t == 0) {
        float S = ps[0] + ps[1] + ps[2] + ps[3];
        float SS = pss[0] + pss[1] + pss[2] + pss[3];
        float m = S * (1.0f / 1024.0f);
        float var = SS * (1.0f / 1024.0f) - m * m;
        stat[0] = m; stat[1] = rsqrtf(var + 1e-5f);
    }
    __syncthreads();
    float m = stat[0], r = stat[1];
    float4 gg = ((const float4*)g)[t];
    float4 bb = ((const float4*)bv)[t];
    ushort4 o;
    o.x = f2bf((v.x - m) * r * gg.x + bb.x);
    o.y = f2bf((v.y - m) * r * gg.y + bb.y);
    o.z = f2bf((v.z - m) * r * gg.z + bb.z);
    o.w = f2bf((v.w - m) * r * gg.w + bb.w);
    ((ushort4*)(out + (size_t)row * 1024))[t] = o;
}

// ---------------- ring-pipelined bf16 MFMA GEMM, fused epilogues -----------
// EPI 0: outB = bf16(acc); gridDim.z==2 selects (A,Bt,outB) vs (A2,Bt2,outB2)
// EPI 1: outF = acc + bias[col] + resid[row][col]        (fp32 out)
// EPI 2: outB = bf16(gelu_exact(acc + bias[col]))
template <int EPI, int K>
__global__ __launch_bounds__(256) void gemm_lds(const unsigned short* __restrict__ A,
                                                const unsigned short* __restrict__ Bt,
                                                const unsigned short* __restrict__ A2,
                                                const unsigned short* __restrict__ Bt2,
                                                const float* __restrict__ bias,
                                                const float* __restrict__ resid,
                                                float* __restrict__ outF,
                                                unsigned short* __restrict__ outB,
                                                unsigned short* __restrict__ outB2,
                                                int N) {
    if (EPI == 0 && blockIdx.z) { A = A2; Bt = Bt2; outB = outB2; }

    // 48 KiB: 3 x (8 KiB A + 8 KiB B) ring buffers. Epilogue staging
    // (4 waves x 16x84 fp32 = 21 KiB) aliases this after the final barrier.
    __shared__ __align__(16) char smem[49152];
    unsigned short* lA = (unsigned short*)smem;            // 3 x 4096 shorts
    unsigned short* lB = (unsigned short*)(smem + 24576);  // 3 x 4096 shorts

    const int tid = threadIdx.x;
    const int wave = tid >> 6, lane = tid & 63;
    const int rowf = lane & 15, quad = lane >> 4;

    // ---- XCD-chunked bijective swizzle (m204) for narrow grids ----
    // gridDim.x<=8: linear dispatch puts the gridDim.x blocks sharing one
    // A row-panel on different XCDs -> A re-fetched per XCD. Remap so each
    // XCD owns a contiguous run of blocks (x-fastest inside the run).
    int bx = blockIdx.x, by = blockIdx.y;
    if (gridDim.x <= 8) {
        int nwg = gridDim.x * gridDim.y;
        int lid = by * gridDim.x + bx;
        int q = nwg >> 3, r = nwg & 7;
        int xcd = lid & 7, pos = lid >> 3;
        int nl = (xcd < r ? xcd * (q + 1) : r * (q + 1) + (xcd - r) * q) + pos;
        bx = nl % gridDim.x;
        by = nl / gridDim.x;
    }

    const int m0 = by * 128;
    const int n0 = bx * 128;
    const int wm0 = (wave >> 1) * 64;         // wave sub-tile inside block
    const int wn0 = (wave & 1) * 64;

    // staging: chunk c = tid + iter*256; row = c>>2, kchunk = (c&3)*8 elements
    const int srow = tid >> 2;                // 0..63
    const int skc  = (tid & 3) * 8;           // 0/8/16/24
    const unsigned short* gA0 = A  + (size_t)(m0 + srow) * K + skc;
    const unsigned short* gA1 = A  + (size_t)(m0 + srow + 64) * K + skc;
    const unsigned short* gB0 = Bt + (size_t)(n0 + srow) * K + skc;
    const unsigned short* gB1 = Bt + (size_t)(n0 + srow + 64) * K + skc;

#define STAGE(pa, pb)                                                       \
    do {                                                                    \
        GLL16(gA0, (pa) + (size_t)tid * 8);                                 \
        GLL16(gA1, (pa) + (size_t)(tid + 256) * 8);                         \
        GLL16(gB0, (pb) + (size_t)tid * 8);                                 \
        GLL16(gB1, (pb) + (size_t)(tid + 256) * 8);                         \
        gA0 += 32; gA1 += 32; gB0 += 32; gB1 += 32;                         \
    } while (0)

    fx4 acc[4][4] = {};
    const int NT = K / 32;

    // ring pointers: pa0/pb0 = tile t, pa1/pb1 = tile t+1 (in flight),
    // pa2/pb2 = stage target for tile t+2 (was read at iter t-1).
    unsigned short *pa0 = lA, *pa1 = lA + 4096, *pa2 = lA + 8192;
    unsigned short *pb0 = lB, *pb1 = lB + 4096, *pb2 = lB + 8192;

    // prologue: tiles 0 and 1 in flight (8 vmem ops outstanding per wave)
    STAGE(pa0, pb0);
    STAGE(pa1, pb1);

    for (int t = 0; t < NT; ++t) {
        if (t + 2 < NT) {
            STAGE(pa2, pb2);                                 // 12 outstanding
            asm volatile("s_waitcnt vmcnt(8)" ::: "memory"); // tile t done, 8 in flight
        } else if (t + 1 < NT) {
            asm volatile("s_waitcnt vmcnt(4)" ::: "memory"); // tile t done, 4 in flight
        } else {
            asm volatile("s_waitcnt vmcnt(0)" ::: "memory"); // last tile done
        }
        asm volatile("s_barrier" ::: "memory");              // tile t visible to all

        short8 a[4], b[4];
        #pragma unroll
        for (int i = 0; i < 4; i++)
            a[i] = *(const short8*)(pa0 + (wm0 + 16 * i + rowf) * 32 + quad * 8);
        #pragma unroll
        for (int j = 0; j < 4; j++)
            b[j] = *(const short8*)(pb0 + (wn0 + 16 * j + rowf) * 32 + quad * 8);
        __builtin_amdgcn_s_setprio(1);
        #pragma unroll
        for (int i = 0; i < 4; i++)
            #pragma unroll
            for (int j = 0; j < 4; j++)
                acc[i][j] = __builtin_amdgcn_mfma_f32_16x16x32_bf16(a[i], b[j], acc[i][j], 0, 0, 0);
        __builtin_amdgcn_s_setprio(0);
        // all waves' ds_reads of tile t drained (lgkmcnt before MFMA) -> after
        // this barrier its buffer may be re-staged (it becomes pa2 next iter).
        asm volatile("s_barrier" ::: "memory");

        unsigned short* ta = pa0; pa0 = pa1; pa1 = pa2; pa2 = ta;
        unsigned short* tb = pb0; pb0 = pb1; pb1 = pb2; pb2 = tb;
    }
#undef STAGE

    // ---- epilogue: per-wave LDS transpose -> coalesced vector I/O ----
    // wave-private 16x84 fp32 staging (stride 84: 4*84*4 % 128 = 16 -> 2-way).
    float* st = (float*)smem + wave * 1344;
    const int rl  = lane >> 2;               // 0..15  (local row)
    const int c0l = (lane & 3) * 16;         // 0/16/32/48 (local col base)
    const int colb = n0 + wn0 + c0l;

    #pragma unroll
    for (int i = 0; i < 4; i++) {
        #pragma unroll
        for (int j = 0; j < 4; j++)
            #pragma unroll
            for (int r = 0; r < 4; r++)
                st[(quad * 4 + r) * 84 + 16 * j + rowf] = acc[i][j][r];
        // wave-local RAW on LDS: compiler inserts lgkmcnt; no cross-wave use.
        const int row = m0 + wm0 + 16 * i + rl;
        if (EPI == 1) {
            #pragma unroll
            for (int kk = 0; kk < 4; kk++) {
                float4 v  = *(const float4*)(st + rl * 84 + c0l + 4 * kk);
                float4 bb = *((const float4*)(bias + colb) + kk);
                float4 rr = *((const float4*)(resid + (size_t)row * N + colb) + kk);
                v.x += bb.x + rr.x; v.y += bb.y + rr.y;
                v.z += bb.z + rr.z; v.w += bb.w + rr.w;
                *((float4*)(outF + (size_t)row * N + colb) + kk) = v;
            }
        } else {
            #pragma unroll
            for (int h = 0; h < 2; h++) {
                float4 va = *(const float4*)(st + rl * 84 + c0l + 8 * h);
                float4 vb = *(const float4*)(st + rl * 84 + c0l + 8 * h + 4);
                float f[8] = {va.x, va.y, va.z, va.w, vb.x, vb.y, vb.z, vb.w};
                if (EPI == 2) {
                    float4 ba = *((const float4*)(bias + colb) + 2 * h);
                    float4 bc = *((const float4*)(bias + colb) + 2 * h + 1);
                    float bf[8] = {ba.x, ba.y, ba.z, ba.w, bc.x, bc.y, bc.z, bc.w};
                    #pragma unroll
                    for (int e = 0; e < 8; e++) {
                        float v = f[e] + bf[e];
                        f[e] = 0.5f * v * (1.0f + erff(v * 0.70710678118654752f));
                    }
                }
                ush8 o;
                #pragma unroll
                for (int e = 0; e < 8; e++) o[e] = f2bf(f[e]);
                *(ush8*)(outB + (size_t)row * N + colb + 8 * h) = o;
            }
        }
    }
}

// ---------------- attention: one block per (chunk-local b, h) --------------
__global__ __launch_bounds__(256) void attn_kernel(const unsigned short* __restrict__ Jqkv,
                                                   const unsigned short* __restrict__ Iqkv,
                                                   const float* __restrict__ Wc,
                                                   unsigned short* __restrict__ xout) {
    int b = blockIdx.x >> 4;
    int h = blockIdx.x & 15;
    __shared__ float J[3][15][65];
    __shared__ float I[3][15][65];
    __shared__ float W[64][17];
    __shared__ float P[15][16];

    const unsigned short* Jb = Jqkv + (size_t)b * 15 * 3072 + h * 64;
    const unsigned short* Ib = Iqkv + (size_t)b * 15 * 3072 + h * 64;

    // vectorized 16B loads: 360 chunks of 8 bf16 per stream
    for (int idx = threadIdx.x; idx < 360; idx += 256) {
        int n = idx / 24, rem = idx % 24;
        int r = rem >> 3, d0 = (rem & 7) * 8;
        short8 vj = *(const short8*)(Jb + (size_t)n * 3072 + r * 1024 + d0);
        short8 vi = *(const short8*)(Ib + (size_t)n * 3072 + r * 1024 + d0);
        #pragma unroll
        for (int e = 0; e < 8; e++) {
            J[r][n][d0 + e] = bf2f((unsigned short)vj[e]);
            I[r][n][d0 + e] = bf2f((unsigned short)vi[e]);
        }
    }
    for (int idx = threadIdx.x; idx < 64 * 15; idx += 256)
        W[idx / 15][idx % 15] = Wc[idx];
    __syncthreads();

    for (int idx = threadIdx.x; idx < 225; idx += 256) {
        int q = idx / 15, kk = idx % 15;
        float s = 0.0f;
        #pragma unroll 8
        for (int d = 0; d < 64; d++)
            s += J[0][q][d] * J[1][kk][d] + I[0][q][d] * I[1][kk][d] + I[2][q][d] * W[d][kk];
        P[q][kk] = s * 0.125f;
    }
    __syncthreads();

    if (threadIdx.x < 15) {
        int q = threadIdx.x;
        float mx = -1e30f;
        #pragma unroll
        for (int kk = 0; kk < 15; kk++) mx = fmaxf(mx, P[q][kk]);
        float e[15], sum = 0.0f;
        #pragma unroll
        for (int kk = 0; kk < 15; kk++) { e[kk] = __expf(P[q][kk] - mx); sum += e[kk]; }
        float inv = 1.0f / sum;
        #pragma unroll
        for (int kk = 0; kk < 15; kk++) P[q][kk] = e[kk] * inv;
    }
    __syncthreads();

    // vectorized ushort4 output: 240 chunks of 4
    for (int idx = threadIdx.x; idx < 240; idx += 256) {
        int q = idx >> 4, d0 = (idx & 15) * 4;
        float o0 = 0.0f, o1 = 0.0f, o2 = 0.0f, o3 = 0.0f;
        #pragma unroll
        for (int kk = 0; kk < 15; kk++) {
            float p = P[q][kk];
            o0 += p * J[2][kk][d0 + 0];
            o1 += p * J[2][kk][d0 + 1];
            o2 += p * J[2][kk][d0 + 2];
            o3 += p * J[2][kk][d0 + 3];
        }
        ushort4 o;
        o.x = f2bf(o0); o.y = f2bf(o1); o.z = f2bf(o2); o.w = f2bf(o3);
        *(ushort4*)(xout + ((size_t)b * 15 + q) * 1024 + h * 64 + d0) = o;
    }
}

// ---------------------------------------------------------------------------
extern "C" void kernel_launch(void* const* d_in, const int* in_sizes, int n_in,
                              void* d_out, int out_size, void* d_ws, size_t ws_size,
                              hipStream_t stream) {
    const float* joint_feature    = (const float*)d_in[0];
    const float* relation_feature = (const float*)d_in[1];
    const float* W_Jqkv  = (const float*)d_in[2];
    const float* W_Iqk   = (const float*)d_in[3];
    const float* W_Iconv = (const float*)d_in[4];
    const float* W_proj  = (const float*)d_in[5];
    const float* b_proj  = (const float*)d_in[6];
    const float* g1  = (const float*)d_in[7];
    const float* be1 = (const float*)d_in[8];
    const float* g2  = (const float*)d_in[9];
    const float* be2 = (const float*)d_in[10];
    const float* gj  = (const float*)d_in[11];
    const float* bj  = (const float*)d_in[12];
    const float* W_fc1 = (const float*)d_in[13];
    const float* b_fc1 = (const float*)d_in[14];
    const float* W_fc2 = (const float*)d_in[15];
    const float* b_fc2 = (const float*)d_in[16];

    char* ws = (char*)d_ws;
    // -------- fixed region [0, 205,520,896) --------
    unsigned short* WtJ  = (unsigned short*)(ws + 0);          //  [3072][1024]
    unsigned short* WtI  = (unsigned short*)(ws + 6291456);    //  [3072][1024]
    unsigned short* WtP  = (unsigned short*)(ws + 12582912);   //  [1024][1024]
    unsigned short* WtF1 = (unsigned short*)(ws + 14680064);   //  [512][1024]
    unsigned short* WtF2 = (unsigned short*)(ws + 15728640);   //  [1024][512]
    unsigned short* xj   = (unsigned short*)(ws + 16777216);   //  [M][1024] bf16
    unsigned short* xi   = (unsigned short*)(ws + 79691776);   //  [M][1024] bf16
    unsigned short* xattn = (unsigned short*)(ws + 142606336); //  [M][1024] bf16
    // -------- reused regions --------
    float*          joint = (float*)(ws + 16777216);           // fp32 [M][1024] over dead xj+xi
    unsigned short* yln   = xattn;                             // xattn dead after proj
    unsigned short* h1    = (unsigned short*)(ws + 205520896); // bf16 [M][512]
    // -------- chunked qkv region --------
    int CH = 16;
    {
        const int opts[5] = {1, 2, 4, 8, 16};
        for (int i = 0; i < 5; i++) {
            size_t need = 205520896ull + 754974720ull / (size_t)opts[i];
            if (need <= ws_size) { CH = opts[i]; break; }
        }
    }
    const int Mc = MROWS / CH;                      // multiple of 1920
    const size_t chunkBytes = 754974720ull / (size_t)CH / 2ull;
    unsigned short* Jqkv_c = (unsigned short*)(ws + 205520896);
    unsigned short* Iqkv_c = (unsigned short*)(ws + 205520896 + chunkBytes);

    dim3 blk(256);

    // 1) transpose + bf16-cast weights
    transpose_w<<<dim3(96, 32), blk, 0, stream>>>(W_Jqkv, WtJ, 1024, 3072);
    transpose_w<<<dim3(96, 32), blk, 0, stream>>>(W_Iqk,  WtI, 1024, 3072);
    transpose_w<<<dim3(32, 32), blk, 0, stream>>>(W_proj, WtP, 1024, 1024);
    transpose_w<<<dim3(16, 32), blk, 0, stream>>>(W_fc1, WtF1, 1024, 512);
    transpose_w<<<dim3(32, 16), blk, 0, stream>>>(W_fc2, WtF2, 512, 1024);

    // 2) LN both input streams -> bf16
    ln_dual<<<dim3(MROWS, 2), blk, 0, stream>>>(joint_feature, g1, be1, xj,
                                                relation_feature, g2, be2, xi);

    // 3+4) chunked: qkv GEMM (both streams via grid.z) then attention
    for (int c = 0; c < CH; c++) {
        size_t ro = (size_t)c * Mc * 1024;
        gemm_lds<0, 1024><<<dim3(24, Mc / 128, 2), blk, 0, stream>>>(
            xj + ro, WtJ, xi + ro, WtI, nullptr, nullptr, nullptr, Jqkv_c, Iqkv_c, 3072);
        attn_kernel<<<(Mc / 15) * 16, blk, 0, stream>>>(Jqkv_c, Iqkv_c, W_Iconv, xattn + ro);
    }

    // 5) proj + bias + residual(joint_feature) -> joint (fp32)
    gemm_lds<1, 1024><<<dim3(8, 240), blk, 0, stream>>>(
        xattn, WtP, nullptr, nullptr, b_proj, joint_feature, joint, nullptr, nullptr, 1024);

    // 6) LN(joint) -> yln
    ln_dual<<<dim3(MROWS, 1), blk, 0, stream>>>(joint, gj, bj, yln,
                                                nullptr, nullptr, nullptr, nullptr);

    // 7) fc1 + bias + gelu -> h1 (bf16)
    gemm_lds<2, 1024><<<dim3(4, 240), blk, 0, stream>>>(
        yln, WtF1, nullptr, nullptr, b_fc1, nullptr, nullptr, h1, nullptr, 512);

    // 8) fc2 + bias + residual(joint) -> d_out (fp32)
    gemm_lds<1, 512><<<dim3(8, 240), blk, 0, stream>>>(
        h1, WtF2, nullptr, nullptr, b_fc2, joint, (float*)d_out, nullptr, nullptr, 1024);
}

// Round 3
// 1368.474 us; speedup vs baseline: 1.0641x; 1.0539x over previous
//
#include <hip/hip_runtime.h>
#include <math.h>

// ---------------------------------------------------------------------------
// B=2048, N=15, C=1024, H=16, HS=64; M = B*N = 30720 rows.
// All GEMMs: A[M][K] bf16 x Bt[N][K] bf16 (weights pre-transposed) -> C.
//
// gemm256: 256x256 block tile, BK=64, 512 threads = 8 waves (2M x 4N),
// per-wave 128x64 output (acc[8][4] of 16x16 frags). 128 KiB LDS double
// buffer {A0,A1,B0,B1} x 16 KiB x 2. 8-phase-style schedule (4 phases per
// K-tile): each phase = {1 half-tile global_load_lds issue || ds_read_b128
// subtile || 16 MFMA wrapped in setprio}. Barriers only after ph1/ph2/ph3;
// ONE counted s_waitcnt vmcnt(4) per K-tile (never 0 mid-loop) -> 2
// half-tiles always in flight. LDS XOR-swizzle (slot ^= row&7) applied as
// pre-swizzled GLOBAL source + swizzled ds_read (linear gload_lds dest),
// killing the 16-way bank conflict of row-stride-128B b128 reads.
// Stage-ahead schedule (region is re-staged >=1 barrier after its last
// reader): ph0: A1(t+1) ph1: B1(t+1) ph2: B0(t+2) ph3: A0(t+2).
// MFMA verified layouts:
//   A frag : lane holds A[m=lane&15][k=(lane>>4)*8+j], j=0..7
//   B frag : lane holds B[k=(lane>>4)*8+j][n=lane&15]  (== Bt[n][k] rows)
//   D      : lane reg r holds D[row=(lane>>4)*4+r][col=lane&15]
// Epilogue: acc -> per-wave LDS staging (16x68 f32) -> coalesced
// float4/ushort4 I/O. Row guard (Mtot) for qkv chunk tails.
//
// ws-ADAPTIVE: qkv processed in CH chunks of 30720/CH rows
// (CH in {1,2,4,8,16}; chunk multiple of 1920 = lcm(128,15); M-tail of the
// 256-row tiling handled by the row guard).
// peak ws = 205,520,896 + 754,974,720/CH bytes.
// ---------------------------------------------------------------------------

typedef __attribute__((ext_vector_type(8))) short short8;
typedef __attribute__((ext_vector_type(4))) float fx4;

#define MROWS 30720

// global(AS1) -> LDS(AS3) 16-byte async copy; LDS dest = wave-uniform base + lane*16
#define GLL16(g, l)                                                         \
    __builtin_amdgcn_global_load_lds(                                       \
        (const __attribute__((address_space(1))) unsigned int*)(g),         \
        (__attribute__((address_space(3))) unsigned int*)(l), 16, 0, 0)

__device__ inline unsigned short f2bf(float f) {
    unsigned int u = __float_as_uint(f);
    unsigned int r = (u + 0x7fffu + ((u >> 16) & 1u)) >> 16;
    return (unsigned short)r;
}
__device__ inline float bf2f(unsigned short s) {
    return __uint_as_float(((unsigned int)s) << 16);
}

// ---------------- weight transpose + bf16 cast:  W[K][N] -> Wt[N][K] --------
__global__ __launch_bounds__(256) void transpose_w(const float* __restrict__ W,
                                                   unsigned short* __restrict__ Wt,
                                                   int K, int N) {
    __shared__ float tile[32][33];
    int bn = blockIdx.x * 32;
    int bk = blockIdx.y * 32;
    int tx = threadIdx.x & 31, ty = threadIdx.x >> 5;   // 32 x 8
    #pragma unroll
    for (int i = ty; i < 32; i += 8)
        tile[i][tx] = W[(size_t)(bk + i) * N + bn + tx];
    __syncthreads();
    #pragma unroll
    for (int i = ty; i < 32; i += 8)
        Wt[(size_t)(bn + i) * K + bk + tx] = f2bf(tile[tx][i]);
}

// ---------------- LayerNorm over C=1024, fp32 in -> bf16 out ---------------
__global__ __launch_bounds__(256) void ln_dual(const float* __restrict__ xa,
                                               const float* __restrict__ ga,
                                               const float* __restrict__ bba,
                                               unsigned short* __restrict__ oa,
                                               const float* __restrict__ xb,
                                               const float* __restrict__ gb,
                                               const float* __restrict__ bbb,
                                               unsigned short* __restrict__ ob) {
    const float* x = blockIdx.y ? xb : xa;
    const float* g = blockIdx.y ? gb : ga;
    const float* bv = blockIdx.y ? bbb : bba;
    unsigned short* out = blockIdx.y ? ob : oa;

    int row = blockIdx.x;
    int t = threadIdx.x;
    const float4* xp = (const float4*)(x + (size_t)row * 1024);
    float4 v = xp[t];
    float s  = v.x + v.y + v.z + v.w;
    float ss = v.x * v.x + v.y * v.y + v.z * v.z + v.w * v.w;
    #pragma unroll
    for (int o = 32; o > 0; o >>= 1) { s += __shfl_down(s, o); ss += __shfl_down(ss, o); }
    __shared__ float ps[4], pss[4], stat[2];
    int wv = t >> 6, ln = t & 63;
    if (ln == 0) { ps[wv] = s; pss[wv] = ss; }
    __syncthreads();
    if (t == 0) {
        float S = ps[0] + ps[1] + ps[2] + ps[3];
        float SS = pss[0] + pss[1] + pss[2] + pss[3];
        float m = S * (1.0f / 1024.0f);
        float var = SS * (1.0f / 1024.0f) - m * m;
        stat[0] = m; stat[1] = rsqrtf(var + 1e-5f);
    }
    __syncthreads();
    float m = stat[0], r = stat[1];
    float4 gg = ((const float4*)g)[t];
    float4 bb = ((const float4*)bv)[t];
    ushort4 o;
    o.x = f2bf((v.x - m) * r * gg.x + bb.x);
    o.y = f2bf((v.y - m) * r * gg.y + bb.y);
    o.z = f2bf((v.z - m) * r * gg.z + bb.z);
    o.w = f2bf((v.w - m) * r * gg.w + bb.w);
    ((ushort4*)(out + (size_t)row * 1024))[t] = o;
}

// ---------------- 256^2 8-phase-style bf16 MFMA GEMM, fused epilogues ------
// EPI 0: outB = bf16(acc); gridDim.z==2 selects (A,Bt,outB) vs (A2,Bt2,outB2)
// EPI 1: outF = acc + bias[col] + resid[row][col]        (fp32 out)
// EPI 2: outB = bf16(gelu_exact(acc + bias[col]))
template <int EPI, int K>
__global__ __launch_bounds__(512, 2) void gemm256(const unsigned short* __restrict__ A,
                                                  const unsigned short* __restrict__ Bt,
                                                  const unsigned short* __restrict__ A2,
                                                  const unsigned short* __restrict__ Bt2,
                                                  const float* __restrict__ bias,
                                                  const float* __restrict__ resid,
                                                  float* __restrict__ outF,
                                                  unsigned short* __restrict__ outB,
                                                  unsigned short* __restrict__ outB2,
                                                  int N, int Mtot) {
    if (EPI == 0 && blockIdx.z) { A = A2; Bt = Bt2; outB = outB2; }

    // 2 bufs x {A0@0, A1@8192, B0@16384, B1@24576} ushorts (16 KiB each half)
    __shared__ unsigned short sm[65536];   // 128 KiB

    const int tid = threadIdx.x;
    const int wid = tid >> 6, lane = tid & 63;
    const int rowf = lane & 15, quad = lane >> 4;
    const int wrow = wid >> 2, wcol = wid & 3;

    // ---- XCD-chunked bijective swizzle (m204) ----
    int bx = blockIdx.x, by = blockIdx.y;
    {
        int nwg = gridDim.x * gridDim.y;
        int lid = by * gridDim.x + bx;
        int q = nwg >> 3, r = nwg & 7;
        int xcd = lid & 7, pos = lid >> 3;
        int nl = (xcd < r ? xcd * (q + 1) : r * (q + 1) + (xcd - r) * q) + pos;
        bx = nl % gridDim.x;
        by = nl / gridDim.x;
    }
    const int m0 = by * 256, n0 = bx * 256;

    // ---- staging source pointers (pre-swizzled global column) ----
    // half-tile = [128 rows][64 k] bf16 = 16 KiB; 2 gload issues (8 KiB each).
    // thread t, issue i: row = i*64 + (t>>3); 16B-slot = (t&7) ^ (row&7).
    const int srw  = tid >> 3;
    const int scol = ((tid & 7) ^ (srw & 7)) << 3;     // bf16 elems
    const unsigned short* pA[2][2];
    const unsigned short* pB[2][2];
    #pragma unroll
    for (int h = 0; h < 2; h++)
        #pragma unroll
        for (int i = 0; i < 2; i++) {
            pA[h][i] = A  + (size_t)(m0 + h * 128 + i * 64 + srw) * K + scol;
            pB[h][i] = Bt + (size_t)(n0 + h * 128 + i * 64 + srw) * K + scol;
        }

    // ds_read lane offsets (ushorts), slot ^= rowf&7 swizzle
    const int axk0 = rowf * 64 + ((quad ^ (rowf & 7)) << 3);
    const int axk1 = rowf * 64 + (((4 + quad) ^ (rowf & 7)) << 3);

    fx4 acc[8][4] = {};
    short8 a[4][2], b[4][2];
    const int NT = K / 64;

#define STG_A(H, D)                                                         \
    do {                                                                    \
        GLL16(pA[H][0], sm + ((D) << 15) + (H) * 8192 + wid * 512);         \
        GLL16(pA[H][1], sm + ((D) << 15) + (H) * 8192 + 4096 + wid * 512);  \
        pA[H][0] += 64; pA[H][1] += 64;                                     \
    } while (0)
#define STG_B(H, D)                                                         \
    do {                                                                    \
        GLL16(pB[H][0], sm + ((D) << 15) + 16384 + (H) * 8192 + wid * 512); \
        GLL16(pB[H][1], sm + ((D) << 15) + 16384 + (H) * 8192 + 4096 + wid * 512); \
        pB[H][0] += 64; pB[H][1] += 64;                                     \
    } while (0)
#define LDA4(BUFO, MS)                                                      \
    do {                                                                    \
        const unsigned short* _p = sm + (BUFO) + wrow * 8192 + (MS) * 4096; \
        _Pragma("unroll") for (int mi = 0; mi < 4; mi++) {                  \
            a[mi][0] = *(const short8*)(_p + mi * 1024 + axk0);             \
            a[mi][1] = *(const short8*)(_p + mi * 1024 + axk1);             \
        }                                                                   \
    } while (0)
#define LDB2(BUFO, PR)                                                      \
    do {                                                                    \
        const unsigned short* _p = sm + (BUFO) + 16384 + (wcol >> 1) * 8192 \
                                   + (wcol & 1) * 4096 + (PR) * 2048;       \
        _Pragma("unroll") for (int ni = 0; ni < 2; ni++) {                  \
            b[(PR) * 2 + ni][0] = *(const short8*)(_p + ni * 1024 + axk0);  \
            b[(PR) * 2 + ni][1] = *(const short8*)(_p + ni * 1024 + axk1);  \
        }                                                                   \
    } while (0)
#define MM16(MS, PR)                                                        \
    do {                                                                    \
        __builtin_amdgcn_s_setprio(1);                                      \
        _Pragma("unroll") for (int mi = 0; mi < 4; mi++)                    \
        _Pragma("unroll") for (int ni = 0; ni < 2; ni++) {                  \
            fx4 _c = acc[(MS) * 4 + mi][(PR) * 2 + ni];                     \
            _c = __builtin_amdgcn_mfma_f32_16x16x32_bf16(a[mi][0], b[(PR) * 2 + ni][0], _c, 0, 0, 0); \
            _c = __builtin_amdgcn_mfma_f32_16x16x32_bf16(a[mi][1], b[(PR) * 2 + ni][1], _c, 0, 0, 0); \
            acc[(MS) * 4 + mi][(PR) * 2 + ni] = _c;                         \
        }                                                                   \
        __builtin_amdgcn_s_setprio(0);                                      \
    } while (0)

    // ---- prologue: tile0 fully + tile1 {B0, A0} (queue-order matters) ----
    STG_A(0, 0); STG_A(1, 0); STG_B(0, 0); STG_B(1, 0);   // tile0 -> buf0
    STG_B(0, 1);                                          // tile1 B0 -> buf1
    STG_A(0, 1);                                          // tile1 A0 -> buf1
    asm volatile("s_waitcnt vmcnt(4)" ::: "memory");      // tile0 landed
    __builtin_amdgcn_s_barrier();

    #pragma unroll 2
    for (int t = 0; t < NT; ++t) {
        const int bufo = (t & 1) << 15;
        const bool s1 = (t + 1 < NT);
        const bool s2 = (t + 2 < NT);

        // ph0: stage A1(t+1); read A msel0 + B pair0; MFMA (m0-3 x n0-1)
        if (s1) STG_A(1, (t + 1) & 1);
        LDA4(bufo, 0);
        LDB2(bufo, 0);
        MM16(0, 0);
        // (no barrier: next stage targets a region free since last tile)

        // ph1: stage B1(t+1); read B pair1; MFMA (m0-3 x n2-3)
        if (s1) STG_B(1, (t + 1) & 1);
        LDB2(bufo, 1);
        MM16(0, 1);
        __builtin_amdgcn_sched_barrier(0);
        __builtin_amdgcn_s_barrier();      // frees B0/B1 of current buf

        // ph2: stage B0(t+2) into current buf; read A msel1; MFMA (m4-7 x n2-3)
        if (s2) STG_B(0, t & 1);
        LDA4(bufo, 1);
        MM16(1, 1);
        __builtin_amdgcn_sched_barrier(0);
        __builtin_amdgcn_s_barrier();      // frees A0/A1 of current buf

        // ph3: stage A0(t+2) into current buf; MFMA (m4-7 x n0-1); counted wait
        if (s2) STG_A(0, t & 1);
        MM16(1, 0);
        if (s1) {
            if (s2) asm volatile("s_waitcnt vmcnt(4)" ::: "memory"); // tile t+1 landed, 2 halves in flight
            else    asm volatile("s_waitcnt vmcnt(0)" ::: "memory"); // last prefetched tile
        }
        __builtin_amdgcn_sched_barrier(0);
        __builtin_amdgcn_s_barrier();      // validates tile t+1 for ph0 reads
    }
#undef STG_A
#undef STG_B
#undef LDA4
#undef LDB2
#undef MM16

    // ---- epilogue: per-wave LDS transpose -> coalesced vector I/O ----
    // wave-private 16x68 f32 staging in (dead) buf0 region.
    float* st = (float*)sm + wid * 1088;
    const int c4 = lane & 15;
    const int rquad = lane >> 4;
    const int colb = n0 + wcol * 64 + c4 * 4;
    float4 bb4 = {0.0f, 0.0f, 0.0f, 0.0f};
    if (EPI != 0) bb4 = *(const float4*)(bias + colb);

    #pragma unroll
    for (int mf = 0; mf < 8; mf++) {
        #pragma unroll
        for (int nf = 0; nf < 4; nf++)
            #pragma unroll
            for (int r = 0; r < 4; r++)
                st[(quad * 4 + r) * 68 + nf * 16 + rowf] = acc[mf][nf][r];
        // wave-local RAW on LDS: compiler inserts lgkmcnt; regions per-wave.
        #pragma unroll
        for (int rr = 0; rr < 4; rr++) {
            int lrow = rr * 4 + rquad;
            float4 v = *(const float4*)(st + lrow * 68 + c4 * 4);
            int grow = m0 + wrow * 128 + mf * 16 + lrow;
            if (grow < Mtot) {
                size_t off = (size_t)grow * N + colb;
                if (EPI == 1) {
                    float4 rr4 = *(const float4*)(resid + off);
                    v.x += bb4.x + rr4.x; v.y += bb4.y + rr4.y;
                    v.z += bb4.z + rr4.z; v.w += bb4.w + rr4.w;
                    *(float4*)(outF + off) = v;
                } else if (EPI == 2) {
                    float f0 = v.x + bb4.x, f1 = v.y + bb4.y;
                    float f2 = v.z + bb4.z, f3 = v.w + bb4.w;
                    f0 = 0.5f * f0 * (1.0f + erff(f0 * 0.70710678118654752f));
                    f1 = 0.5f * f1 * (1.0f + erff(f1 * 0.70710678118654752f));
                    f2 = 0.5f * f2 * (1.0f + erff(f2 * 0.70710678118654752f));
                    f3 = 0.5f * f3 * (1.0f + erff(f3 * 0.70710678118654752f));
                    ushort4 o;
                    o.x = f2bf(f0); o.y = f2bf(f1); o.z = f2bf(f2); o.w = f2bf(f3);
                    *(ushort4*)(outB + off) = o;
                } else {
                    ushort4 o;
                    o.x = f2bf(v.x); o.y = f2bf(v.y); o.z = f2bf(v.z); o.w = f2bf(v.w);
                    *(ushort4*)(outB + off) = o;
                }
            }
        }
    }
}

// ---------------- attention: one block per (chunk-local b, h) --------------
__global__ __launch_bounds__(256) void attn_kernel(const unsigned short* __restrict__ Jqkv,
                                                   const unsigned short* __restrict__ Iqkv,
                                                   const float* __restrict__ Wc,
                                                   unsigned short* __restrict__ xout) {
    int b = blockIdx.x >> 4;
    int h = blockIdx.x & 15;
    __shared__ float J[3][15][65];
    __shared__ float I[3][15][65];
    __shared__ float W[64][17];
    __shared__ float P[15][16];

    const unsigned short* Jb = Jqkv + (size_t)b * 15 * 3072 + h * 64;
    const unsigned short* Ib = Iqkv + (size_t)b * 15 * 3072 + h * 64;

    // vectorized 16B loads: 360 chunks of 8 bf16 per stream
    for (int idx = threadIdx.x; idx < 360; idx += 256) {
        int n = idx / 24, rem = idx % 24;
        int r = rem >> 3, d0 = (rem & 7) * 8;
        short8 vj = *(const short8*)(Jb + (size_t)n * 3072 + r * 1024 + d0);
        short8 vi = *(const short8*)(Ib + (size_t)n * 3072 + r * 1024 + d0);
        #pragma unroll
        for (int e = 0; e < 8; e++) {
            J[r][n][d0 + e] = bf2f((unsigned short)vj[e]);
            I[r][n][d0 + e] = bf2f((unsigned short)vi[e]);
        }
    }
    for (int idx = threadIdx.x; idx < 64 * 15; idx += 256)
        W[idx / 15][idx % 15] = Wc[idx];
    __syncthreads();

    for (int idx = threadIdx.x; idx < 225; idx += 256) {
        int q = idx / 15, kk = idx % 15;
        float s = 0.0f;
        #pragma unroll 8
        for (int d = 0; d < 64; d++)
            s += J[0][q][d] * J[1][kk][d] + I[0][q][d] * I[1][kk][d] + I[2][q][d] * W[d][kk];
        P[q][kk] = s * 0.125f;
    }
    __syncthreads();

    if (threadIdx.x < 15) {
        int q = threadIdx.x;
        float mx = -1e30f;
        #pragma unroll
        for (int kk = 0; kk < 15; kk++) mx = fmaxf(mx, P[q][kk]);
        float e[15], sum = 0.0f;
        #pragma unroll
        for (int kk = 0; kk < 15; kk++) { e[kk] = __expf(P[q][kk] - mx); sum += e[kk]; }
        float inv = 1.0f / sum;
        #pragma unroll
        for (int kk = 0; kk < 15; kk++) P[q][kk] = e[kk] * inv;
    }
    __syncthreads();

    // vectorized ushort4 output: 240 chunks of 4
    for (int idx = threadIdx.x; idx < 240; idx += 256) {
        int q = idx >> 4, d0 = (idx & 15) * 4;
        float o0 = 0.0f, o1 = 0.0f, o2 = 0.0f, o3 = 0.0f;
        #pragma unroll
        for (int kk = 0; kk < 15; kk++) {
            float p = P[q][kk];
            o0 += p * J[2][kk][d0 + 0];
            o1 += p * J[2][kk][d0 + 1];
            o2 += p * J[2][kk][d0 + 2];
            o3 += p * J[2][kk][d0 + 3];
        }
        ushort4 o;
        o.x = f2bf(o0); o.y = f2bf(o1); o.z = f2bf(o2); o.w = f2bf(o3);
        *(ushort4*)(xout + ((size_t)b * 15 + q) * 1024 + h * 64 + d0) = o;
    }
}

// ---------------------------------------------------------------------------
extern "C" void kernel_launch(void* const* d_in, const int* in_sizes, int n_in,
                              void* d_out, int out_size, void* d_ws, size_t ws_size,
                              hipStream_t stream) {
    const float* joint_feature    = (const float*)d_in[0];
    const float* relation_feature = (const float*)d_in[1];
    const float* W_Jqkv  = (const float*)d_in[2];
    const float* W_Iqk   = (const float*)d_in[3];
    const float* W_Iconv = (const float*)d_in[4];
    const float* W_proj  = (const float*)d_in[5];
    const float* b_proj  = (const float*)d_in[6];
    const float* g1  = (const float*)d_in[7];
    const float* be1 = (const float*)d_in[8];
    const float* g2  = (const float*)d_in[9];
    const float* be2 = (const float*)d_in[10];
    const float* gj  = (const float*)d_in[11];
    const float* bj  = (const float*)d_in[12];
    const float* W_fc1 = (const float*)d_in[13];
    const float* b_fc1 = (const float*)d_in[14];
    const float* W_fc2 = (const float*)d_in[15];
    const float* b_fc2 = (const float*)d_in[16];

    char* ws = (char*)d_ws;
    // -------- fixed region [0, 205,520,896) --------
    unsigned short* WtJ  = (unsigned short*)(ws + 0);          //  [3072][1024]
    unsigned short* WtI  = (unsigned short*)(ws + 6291456);    //  [3072][1024]
    unsigned short* WtP  = (unsigned short*)(ws + 12582912);   //  [1024][1024]
    unsigned short* WtF1 = (unsigned short*)(ws + 14680064);   //  [512][1024]
    unsigned short* WtF2 = (unsigned short*)(ws + 15728640);   //  [1024][512]
    unsigned short* xj   = (unsigned short*)(ws + 16777216);   //  [M][1024] bf16
    unsigned short* xi   = (unsigned short*)(ws + 79691776);   //  [M][1024] bf16
    unsigned short* xattn = (unsigned short*)(ws + 142606336); //  [M][1024] bf16
    // -------- reused regions --------
    float*          joint = (float*)(ws + 16777216);           // fp32 [M][1024] over dead xj+xi
    unsigned short* yln   = xattn;                             // xattn dead after proj
    unsigned short* h1    = (unsigned short*)(ws + 205520896); // bf16 [M][512]
    // -------- chunked qkv region --------
    int CH = 16;
    {
        const int opts[5] = {1, 2, 4, 8, 16};
        for (int i = 0; i < 5; i++) {
            size_t need = 205520896ull + 754974720ull / (size_t)opts[i];
            if (need <= ws_size) { CH = opts[i]; break; }
        }
    }
    const int Mc = MROWS / CH;                      // multiple of 1920
    const size_t chunkBytes = 754974720ull / (size_t)CH / 2ull;
    unsigned short* Jqkv_c = (unsigned short*)(ws + 205520896);
    unsigned short* Iqkv_c = (unsigned short*)(ws + 205520896 + chunkBytes);

    dim3 blk(256);
    dim3 blk5(512);

    // 1) transpose + bf16-cast weights
    transpose_w<<<dim3(96, 32), blk, 0, stream>>>(W_Jqkv, WtJ, 1024, 3072);
    transpose_w<<<dim3(96, 32), blk, 0, stream>>>(W_Iqk,  WtI, 1024, 3072);
    transpose_w<<<dim3(32, 32), blk, 0, stream>>>(W_proj, WtP, 1024, 1024);
    transpose_w<<<dim3(16, 32), blk, 0, stream>>>(W_fc1, WtF1, 1024, 512);
    transpose_w<<<dim3(32, 16), blk, 0, stream>>>(W_fc2, WtF2, 512, 1024);

    // 2) LN both input streams -> bf16
    ln_dual<<<dim3(MROWS, 2), blk, 0, stream>>>(joint_feature, g1, be1, xj,
                                                relation_feature, g2, be2, xi);

    // 3+4) chunked: qkv GEMM (both streams via grid.z) then attention
    const int My = (Mc + 255) >> 8;
    for (int c = 0; c < CH; c++) {
        size_t ro = (size_t)c * Mc * 1024;
        gemm256<0, 1024><<<dim3(12, My, 2), blk5, 0, stream>>>(
            xj + ro, WtJ, xi + ro, WtI, nullptr, nullptr, nullptr, Jqkv_c, Iqkv_c, 3072, Mc);
        attn_kernel<<<(Mc / 15) * 16, blk, 0, stream>>>(Jqkv_c, Iqkv_c, W_Iconv, xattn + ro);
    }

    // 5) proj + bias + residual(joint_feature) -> joint (fp32)
    gemm256<1, 1024><<<dim3(4, 120), blk5, 0, stream>>>(
        xattn, WtP, nullptr, nullptr, b_proj, joint_feature, joint, nullptr, nullptr, 1024, MROWS);

    // 6) LN(joint) -> yln
    ln_dual<<<dim3(MROWS, 1), blk, 0, stream>>>(joint, gj, bj, yln,
                                                nullptr, nullptr, nullptr, nullptr);

    // 7) fc1 + bias + gelu -> h1 (bf16)
    gemm256<2, 1024><<<dim3(2, 120), blk5, 0, stream>>>(
        yln, WtF1, nullptr, nullptr, b_fc1, nullptr, nullptr, h1, nullptr, 512, MROWS);

    // 8) fc2 + bias + residual(joint) -> d_out (fp32)
    gemm256<1, 512><<<dim3(4, 120), blk5, 0, stream>>>(
        h1, WtF2, nullptr, nullptr, b_fc2, joint, (float*)d_out, nullptr, nullptr, 1024, MROWS);
}